// Round 13
// baseline (230.188 us; speedup 1.0000x reference)
//
#include <hip/hip_runtime.h>

// SSIM (skimage default): 7x7 uniform filter, valid crop (pad=3), sample cov.
// Images: 4096x4096 fp32, output region 4090x4090, result = mean(S) scalar.
//
// R13: circular-row LDS pipeline. R12 (full-strip 58KB stage) tied R9 at
// 72us: LDS reads ARE hideable at 2 blocks/CU, but 58KB cost a residency
// block and 1.75x staging re-read ate the win. Fix both with a 10-row
// circular buffer (41.6KB -> 3 blocks/CU) over 28 output rows/block:
//  - staging ratio 1.29x (h/output 1.21 vs 1.75);
//  - per phase (2 output rows): stage_load (1 float4/img/thread, prefetch
//    for phase p+1) BEFORE compute, stage_write AFTER compute, one barrier
//    at phase end. vmcnt-wait lands at the ds_write = after compute
//    (structural overlap, not scheduler-dependent).
//  - slot safety: stage p writes slots (2p-2,2p-1)%10; compute p reads
//    (2p..2p+7)%10 - disjoint; barrier covers phase p-1's reads.
//  - codegen rules R1-R8 kept: 14 phases = 2 chunks of 7 (pb in {0,7},
//    runtime loop; (2pb)%7==0 so ring slots (2pu+d)%7 stay compile-time);
//    runtime rows_in guard around compute; ring[7][10] in AGPRs.
//  - epilogue algebra (R8/R9) + single-kernel atomic (R10) kept.
// History: R0 92 -> R4 74.5 -> R9/R10 72 (L3-direct) -> R11 95 -> R12 72.3
// (LDS full-strip, 2 blk/CU). Falsifiers: WRITE>10MB = spill -> revert;
// dur >= 72us -> declare 72 the structural floor.

#define W_IMG   4096
#define H_IMG   4096
#define OW      4090
#define OH      4090
#define RBLK    28            // output rows per block
#define NPH     14            // phases (2 output rows each)
#define RBUF    10            // circular LDS row slots
#define NTHR    256
#define CPB     512           // output columns per block (2 per thread)
#define LDS_W   520           // row stride in floats (518 used + pad)

// generic-pointer hsums (LDS source; emits ds_read_b64)
__device__ __forceinline__ void hsums(const float* pO, const float* pT,
                                      float h[10])
{
    float2 a0 = *(const float2*)(pO + 0);
    float2 a1 = *(const float2*)(pO + 2);
    float2 a2 = *(const float2*)(pO + 4);
    float2 a3 = *(const float2*)(pO + 6);
    float2 b0 = *(const float2*)(pT + 0);
    float2 b1 = *(const float2*)(pT + 2);
    float2 b2 = *(const float2*)(pT + 4);
    float2 b3 = *(const float2*)(pT + 6);
    float o0=a0.x,o1=a0.y,o2=a1.x,o3=a1.y,o4=a2.x,o5=a2.y,o6=a3.x,o7=a3.y;
    float t0=b0.x,t1=b0.y,t2=b1.x,t3=b1.y,t4=b2.x,t5=b2.y,t6=b3.x,t7=b3.y;

    float so  = ((o0+o1)+(o2+o3)) + ((o4+o5)+o6);
    float st  = ((t0+t1)+(t2+t3)) + ((t4+t5)+t6);
    float soo = fmaf(o6,o6, fmaf(o5,o5, fmaf(o4,o4, fmaf(o3,o3, fmaf(o2,o2, fmaf(o1,o1, o0*o0))))));
    float stt = fmaf(t6,t6, fmaf(t5,t5, fmaf(t4,t4, fmaf(t3,t3, fmaf(t2,t2, fmaf(t1,t1, t0*t0))))));
    float sot = fmaf(o6,t6, fmaf(o5,t5, fmaf(o4,t4, fmaf(o3,t3, fmaf(o2,t2, fmaf(o1,t1, o0*t0))))));

    h[0] = so;   h[1] = so  - o0    + o7;
    h[2] = st;   h[3] = st  - t0    + t7;
    h[4] = soo;  h[5] = soo - o0*o0 + o7*o7;
    h[6] = stt;  h[7] = stt - t0*t0 + t7*t7;
    h[8] = sot;  h[9] = sot - o0*t0 + o7*t7;
}

// Scaled SSIM num/den (R8/R9 verified): A1,B1 *= 49^2; A2,B2 *= 48*49.
__device__ __forceinline__ void ssim_nd(const float v[10], int px,
                                        float& num, float& den)
{
    const float K1 = 0.9604f;     // 4.0e-4 * 2401
    const float K2 = 8.4672f;     // 3.6e-3 * 2352
    float so  = v[0+px], st  = v[2+px];
    float soo = v[4+px], stt = v[6+px], sot = v[8+px];
    float t1 = so*st;
    float A1 = fmaf(2.0f, t1, K1);
    float ss = fmaf(st, st, so*so);
    float B1 = ss + K1;
    float A2 = fmaf(98.0f, sot, fmaf(-2.0f, t1, K2));
    float B2 = fmaf(49.0f, soo + stt, K2 - ss);
    num = A1*A2;
    den = B1*B2;
}

__global__ __launch_bounds__(NTHR, 3)
void ssim_main(const float* __restrict__ O, const float* __restrict__ T,
               float* __restrict__ outp)
{
    __shared__ float lds[2][RBUF][LDS_W];   // 41,600 B
    __shared__ float wpart[NTHR / 64];

    const int t   = threadIdx.x;
    const int bxc = blockIdx.x * CPB;
    const int r0  = blockIdx.y * RBLK;
    const int rows_in = min(RBLK, OH - r0);   // runtime (2 on tail strip)

    // ---- staging helpers: 2 rows (lo, lo+1) per call ----
    const int st_rl = t >> 7;                 // my row within the pair (0/1)
    const int st_cg = t & 127;                // my float4 col group
    // halo units: 12 threads cover 2 rows x 2 imgs x 3 float2 (cols 512..517)
    const int hu_f2 = t % 3;
    const int hu_mi = (t / 3) & 1;
    const int hu_rs = t / 6;

    auto stage_load = [&](int lo, float4& sO, float4& sT, float2& hh) {
        const int gr = min(r0 + lo + st_rl, H_IMG - 1);
        sO = *(const float4*)(O + (size_t)gr * W_IMG + bxc + 4*st_cg);
        sT = *(const float4*)(T + (size_t)gr * W_IMG + bxc + 4*st_cg);
        if (t < 12) {
            const int gr2 = min(r0 + lo + hu_rs, H_IMG - 1);
            const int gc  = min(bxc + 512 + 2*hu_f2, W_IMG - 2);
            const float* src = hu_mi ? T : O;
            hh = *(const float2*)(src + (size_t)gr2 * W_IMG + gc);
        }
    };
    auto stage_write = [&](int lo, const float4& sO, const float4& sT,
                           const float2& hh) {
        const int slot = (lo + st_rl) % RBUF;
        *(float4*)&lds[0][slot][4*st_cg] = sO;
        *(float4*)&lds[1][slot][4*st_cg] = sT;
        if (t < 12) {
            const int slot2 = (lo + hu_rs) % RBUF;
            *(float2*)&lds[hu_mi][slot2][512 + 2*hu_f2] = hh;
        }
    };

    // ---- initial stage: input rows 0..7 into slots 0..7 ----
    {
        float4 aO, aT, bO, bT, cO, cT, dO, dT;
        float2 ah, bh, ch, dh;
        stage_load(0, aO, aT, ah);
        stage_load(2, bO, bT, bh);
        stage_load(4, cO, cT, ch);
        stage_load(6, dO, dT, dh);
        stage_write(0, aO, aT, ah);
        stage_write(2, bO, bT, bh);
        stage_write(4, cO, cT, ch);
        stage_write(6, dO, dT, dh);
    }
    __syncthreads();

    const int c0 = bxc + 2*t;                 // first of the 2 output cols
    const bool active = c0 < OW;
    float acc = 0.0f;

    float ring[7][10];   // 7-row delay line of horizontal sums (AGPRs)
    float v[10];
    #pragma unroll
    for (int q = 0; q < 10; q++) v[q] = 0.0f;

    // warm-up: input rows 0..5 (slots 0..5)
    if (active) {
        #pragma unroll
        for (int i = 0; i < 6; i++) {
            float h[10];
            hsums(&lds[0][i][2*t], &lds[1][i][2*t], h);
            #pragma unroll
            for (int q = 0; q < 10; q++) { v[q] += h[q]; ring[i][q] = h[q]; }
        }
    }

    // ---- phase loop: 2 chunks of 7 so ring slots stay compile-time ----
    for (int pb = 0; pb < NPH; pb += 7) {
        #pragma unroll
        for (int pu = 0; pu < 7; pu++) {
            const int p  = pb + pu;
            const int j0 = 2*p, j1 = 2*p + 1;

            // prefetch input rows 8+2p, 9+2p (for phase p+1); write late
            float4 sO, sT; float2 hh;
            stage_load(8 + 2*p, sO, sT, hh);

            if (active && j1 < rows_in) {     // uniform runtime fence
                // --- output row j0 (input row i0 = j0+6) ---
                {
                    const int s0 = (j0 + 6) % RBUF;   // scalar addr math
                    float h[10];
                    hsums(&lds[0][s0][2*t], &lds[1][s0][2*t], h);
                    #pragma unroll
                    for (int q = 0; q < 10; q++) v[q] += h[q];
                    float n0, d0, n1, d1;
                    ssim_nd(v, 0, n0, d0);
                    ssim_nd(v, 1, n1, d1);
                    acc = fmaf(fmaf(n0, d1, n1*d0),
                               __builtin_amdgcn_rcpf(d0*d1), acc);
                    #pragma unroll
                    for (int q = 0; q < 10; q++) {
                        v[q] -= ring[(2*pu) % 7][q];        // h(row j0)
                        ring[(2*pu + 6) % 7][q] = h[q];     // h(row j0+6)
                    }
                }
                // --- output row j1 (input row i1 = j1+6) ---
                {
                    const int s1 = (j1 + 6) % RBUF;
                    float h[10];
                    hsums(&lds[0][s1][2*t], &lds[1][s1][2*t], h);
                    #pragma unroll
                    for (int q = 0; q < 10; q++) v[q] += h[q];
                    float n0, d0, n1, d1;
                    ssim_nd(v, 0, n0, d0);
                    ssim_nd(v, 1, n1, d1);
                    acc = fmaf(fmaf(n0, d1, n1*d0),
                               __builtin_amdgcn_rcpf(d0*d1), acc);
                    #pragma unroll
                    for (int q = 0; q < 10; q++) {
                        v[q] -= ring[(2*pu + 1) % 7][q];    // h(row j1)
                        ring[(2*pu + 7) % 7][q] = h[q];     // h(row j1+6)
                    }
                }
            }

            // vmcnt-wait lands here (first use of staged regs): after compute
            stage_write(8 + 2*p, sO, sT, hh);
            __syncthreads();   // protects slots read this phase from p+1's writes
        }
    }

    // wave(64) shuffle reduction
    #pragma unroll
    for (int off = 32; off; off >>= 1) acc += __shfl_down(acc, off);

    if ((t & 63) == 0) wpart[t >> 6] = acc;
    __syncthreads();
    if (t == 0) {
        float s = 0.0f;
        #pragma unroll
        for (int w = 0; w < NTHR / 64; w++) s += wpart[w];
        const float inv = (float)(1.0 / ((double)OW * (double)OH));
        atomicAdd(outp, s * inv);   // pre-scaled, straight into d_out
    }
}

extern "C" void kernel_launch(void* const* d_in, const int* in_sizes, int n_in,
                              void* d_out, int out_size, void* d_ws, size_t ws_size,
                              hipStream_t stream)
{
    const float* O = (const float*)d_in[0];
    const float* T = (const float*)d_in[1];
    float* out = (float*)d_out;

    hipMemsetAsync(out, 0, sizeof(float), stream);   // accumulate in d_out

    dim3 grid((OW + CPB - 1) / CPB, (OH + RBLK - 1) / RBLK);  // (8, 147)
    ssim_main<<<grid, NTHR, 0, stream>>>(O, T, out);
}